// Round 1
// baseline (1021.728 us; speedup 1.0000x reference)
//
#include <hip/hip_runtime.h>
#include <hip/hip_bf16.h>

#define DEVINL __device__ __forceinline__

typedef __attribute__((ext_vector_type(8))) __bf16 bf16x8;
typedef __attribute__((ext_vector_type(4))) float f32x4;
typedef __attribute__((ext_vector_type(4))) unsigned short us4;

DEVINL unsigned short f2bf(float f) {
  union { float f; unsigned int u; } c;
  c.f = f;
  unsigned int u = c.u;
  u += 0x7fffu + ((u >> 16) & 1u);   // RNE
  return (unsigned short)(u >> 16);
}

// jax.nn.gelu(approximate=True): 0.5x(1+tanh(sqrt(2/pi)(x+0.044715x^3)))
//  = x * sigmoid(2*sqrt(2/pi)*(x + 0.044715 x^3))
DEVINL float gelu_tanh(float x) {
  float t = 1.5957691216057308f * x * __builtin_fmaf(0.044715f, x * x, 1.0f);
  return x / (1.0f + __expf(-t));
}

DEVINL void ld16(const void* g, void* l) {
  __builtin_amdgcn_global_load_lds(
      (const __attribute__((address_space(1))) void*)g,
      (__attribute__((address_space(3))) void*)l, 16, 0, 0);
}

// ---------------- transpose + fp32->bf16 cast: in[R][C] f32 -> out[C][R] bf16
__global__ __launch_bounds__(256) void transpose_cast_kernel(
    const float* __restrict__ in, unsigned short* __restrict__ out, int R, int C) {
  __shared__ float tile[32][33];
  const int t = threadIdx.x;
  const int r0 = blockIdx.x << 5, c0 = blockIdx.y << 5;
  const int tr = t >> 3, tc = (t & 7) << 2;
  const float4 v = *(const float4*)(in + (size_t)(r0 + tr) * C + c0 + tc);
  tile[tr][tc] = v.x; tile[tr][tc + 1] = v.y;
  tile[tr][tc + 2] = v.z; tile[tr][tc + 3] = v.w;
  __syncthreads();
  us4 o;
  o[0] = f2bf(tile[tc + 0][tr]);
  o[1] = f2bf(tile[tc + 1][tr]);
  o[2] = f2bf(tile[tc + 2][tr]);
  o[3] = f2bf(tile[tc + 3][tr]);
  *(us4*)(out + (size_t)(c0 + tr) * R + r0 + tc) = o;
}

// ---------------- LayerNorm: x[8192][2048] f32 -> ln bf16
__global__ __launch_bounds__(256) void ln_kernel(
    const float* __restrict__ x, const float* __restrict__ gamma,
    const float* __restrict__ beta, unsigned short* __restrict__ out) {
  constexpr int H = 2048;
  const int t = threadIdx.x;
  const size_t row = blockIdx.x;
  const float4* xr = (const float4*)(x + row * H);
  const float4 a = xr[t], b = xr[t + 256];
  float s  = a.x + a.y + a.z + a.w + b.x + b.y + b.z + b.w;
  float s2 = a.x*a.x + a.y*a.y + a.z*a.z + a.w*a.w
           + b.x*b.x + b.y*b.y + b.z*b.z + b.w*b.w;
#pragma unroll
  for (int o = 32; o > 0; o >>= 1) { s += __shfl_xor(s, o); s2 += __shfl_xor(s2, o); }
  __shared__ float red[8];
  const int wid = t >> 6, lane = t & 63;
  if (lane == 0) { red[wid] = s; red[4 + wid] = s2; }
  __syncthreads();
  s  = red[0] + red[1] + red[2] + red[3];
  s2 = red[4] + red[5] + red[6] + red[7];
  const float mean = s * (1.0f / H);
  const float rstd = rsqrtf(s2 * (1.0f / H) - mean * mean + 1e-6f);
  const float4 g0 = ((const float4*)gamma)[t], g1 = ((const float4*)gamma)[t + 256];
  const float4 c0 = ((const float4*)beta)[t],  c1 = ((const float4*)beta)[t + 256];
  us4 o0, o1;
  o0[0] = f2bf((a.x - mean) * rstd * g0.x + c0.x);
  o0[1] = f2bf((a.y - mean) * rstd * g0.y + c0.y);
  o0[2] = f2bf((a.z - mean) * rstd * g0.z + c0.z);
  o0[3] = f2bf((a.w - mean) * rstd * g0.w + c0.w);
  o1[0] = f2bf((b.x - mean) * rstd * g1.x + c1.x);
  o1[1] = f2bf((b.y - mean) * rstd * g1.y + c1.y);
  o1[2] = f2bf((b.z - mean) * rstd * g1.z + c1.z);
  o1[3] = f2bf((b.w - mean) * rstd * g1.w + c1.w);
  *(us4*)(out + row * H + (size_t)t * 4) = o0;
  *(us4*)(out + row * H + 1024 + (size_t)t * 4) = o1;
}

// ---------------- GEMM1 + gated GELU:
// A = ln [M][2048] bf16 (K-contig), B = k1T [16384][2048] bf16 (B^T, K-contig)
// z[m][i] = gelu(sum_h A[m][h]*B[i][h]) * (sum_h A[m][h]*B[8192+i][h])
__global__ __launch_bounds__(256, 2) void gemm1_act_kernel(
    const unsigned short* __restrict__ A,
    const unsigned short* __restrict__ B,
    unsigned short* __restrict__ Z) {
  constexpr int K = 2048, NI = 8192;
  __shared__ unsigned short As[128 * 32], Bs0[128 * 32], Bs1[128 * 32];
  const int t = threadIdx.x, lane = t & 63, wid = t >> 6;
  const int wr = wid >> 1, wc = wid & 1;
  const size_t m0 = (size_t)blockIdx.x << 7, n0 = (size_t)blockIdx.y << 7;

  const int srow = t >> 2;                 // 0..63
  const int skb = (t & 3) << 4;            // 0..48 bytes within a 64B k-span
  const char* aP  = (const char*)(A + (m0 + srow) * K) + skb;
  const char* b0P = (const char*)(B + (n0 + srow) * K) + skb;
  const char* b1P = (const char*)(B + ((size_t)NI + n0 + srow) * K) + skb;
  const size_t rstride = (size_t)64 * K * 2;   // +64 rows
  char* lA  = (char*)As  + (wid << 10);
  char* lB0 = (char*)Bs0 + (wid << 10);
  char* lB1 = (char*)Bs1 + (wid << 10);

  f32x4 acc0[4][4] = {}, acc1[4][4] = {};
  const int fr = lane & 15;
  const int fk = (lane >> 4) << 3;

  for (int k0 = 0; k0 < K; k0 += 32) {
    const size_t kb = (size_t)k0 * 2;
    ld16(aP + kb, lA);               ld16(aP + kb + rstride, lA + 4096);
    ld16(b0P + kb, lB0);             ld16(b0P + kb + rstride, lB0 + 4096);
    ld16(b1P + kb, lB1);             ld16(b1P + kb + rstride, lB1 + 4096);
    __syncthreads();   // drains vmcnt -> staged data visible
    bf16x8 af[4], bf0[4], bf1[4];
#pragma unroll
    for (int m = 0; m < 4; ++m)
      af[m] = *(const bf16x8*)(As + ((wr << 6) + (m << 4) + fr) * 32 + fk);
#pragma unroll
    for (int n = 0; n < 4; ++n) {
      bf0[n] = *(const bf16x8*)(Bs0 + ((wc << 6) + (n << 4) + fr) * 32 + fk);
      bf1[n] = *(const bf16x8*)(Bs1 + ((wc << 6) + (n << 4) + fr) * 32 + fk);
    }
#pragma unroll
    for (int m = 0; m < 4; ++m)
#pragma unroll
      for (int n = 0; n < 4; ++n) {
        acc0[m][n] = __builtin_amdgcn_mfma_f32_16x16x32_bf16(af[m], bf0[n], acc0[m][n], 0, 0, 0);
        acc1[m][n] = __builtin_amdgcn_mfma_f32_16x16x32_bf16(af[m], bf1[n], acc1[m][n], 0, 0, 0);
      }
    __syncthreads();   // protect LDS before next stage
  }

  const int fq = (lane >> 4) << 2;
#pragma unroll
  for (int m = 0; m < 4; ++m)
#pragma unroll
    for (int n = 0; n < 4; ++n) {
      const size_t gm = m0 + (wr << 6) + (m << 4) + fq;
      const size_t gi = n0 + (wc << 6) + (n << 4) + fr;
#pragma unroll
      for (int r = 0; r < 4; ++r) {
        const float y0 = acc0[m][n][r];
        const float y1 = acc1[m][n][r];
        Z[(gm + r) * NI + gi] = f2bf(gelu_tanh(y0) * y1);
      }
    }
}

// ---------------- GEMM2: out[m][h] = sum_i z[m][i] * k2T[h][i], fp32 out
__global__ __launch_bounds__(256, 2) void gemm2_kernel(
    const unsigned short* __restrict__ A,   // z [M][8192]
    const unsigned short* __restrict__ B,   // k2T [2048][8192]
    float* __restrict__ Out) {              // [M][2048]
  constexpr int K = 8192, NH = 2048;
  __shared__ unsigned short As[128 * 32], Bs[128 * 32];
  const int t = threadIdx.x, lane = t & 63, wid = t >> 6;
  const int wr = wid >> 1, wc = wid & 1;
  const size_t m0 = (size_t)blockIdx.x << 7, n0 = (size_t)blockIdx.y << 7;

  const int srow = t >> 2;
  const int skb = (t & 3) << 4;
  const char* aP = (const char*)(A + (m0 + srow) * K) + skb;
  const char* bP = (const char*)(B + (n0 + srow) * K) + skb;
  const size_t rstride = (size_t)64 * K * 2;
  char* lA = (char*)As + (wid << 10);
  char* lB = (char*)Bs + (wid << 10);

  f32x4 acc[4][4] = {};
  const int fr = lane & 15;
  const int fk = (lane >> 4) << 3;

  for (int k0 = 0; k0 < K; k0 += 32) {
    const size_t kb = (size_t)k0 * 2;
    ld16(aP + kb, lA);  ld16(aP + kb + rstride, lA + 4096);
    ld16(bP + kb, lB);  ld16(bP + kb + rstride, lB + 4096);
    __syncthreads();
    bf16x8 af[4], bf[4];
#pragma unroll
    for (int m = 0; m < 4; ++m)
      af[m] = *(const bf16x8*)(As + ((wr << 6) + (m << 4) + fr) * 32 + fk);
#pragma unroll
    for (int n = 0; n < 4; ++n)
      bf[n] = *(const bf16x8*)(Bs + ((wc << 6) + (n << 4) + fr) * 32 + fk);
#pragma unroll
    for (int m = 0; m < 4; ++m)
#pragma unroll
      for (int n = 0; n < 4; ++n)
        acc[m][n] = __builtin_amdgcn_mfma_f32_16x16x32_bf16(af[m], bf[n], acc[m][n], 0, 0, 0);
    __syncthreads();
  }

  const int fq = (lane >> 4) << 2;
#pragma unroll
  for (int m = 0; m < 4; ++m)
#pragma unroll
    for (int n = 0; n < 4; ++n) {
      const size_t gm = m0 + (wr << 6) + (m << 4) + fq;
      const size_t gh = n0 + (wc << 6) + (n << 4) + fr;
#pragma unroll
      for (int r = 0; r < 4; ++r)
        Out[(gm + r) * NH + gh] = acc[m][n][r];
    }
}

extern "C" void kernel_launch(void* const* d_in, const int* in_sizes, int n_in,
                              void* d_out, int out_size, void* d_ws, size_t ws_size,
                              hipStream_t stream) {
  const float* x     = (const float*)d_in[0];
  const float* gamma = (const float*)d_in[1];
  const float* beta  = (const float*)d_in[2];
  const float* k1    = (const float*)d_in[3];   // [2048][2][8192] = [2048][16384]
  const float* k2    = (const float*)d_in[4];   // [8192][2048]
  float* out = (float*)d_out;

  const size_t H = 2048, I = 8192, M = 8192;
  unsigned short* k1T = (unsigned short*)d_ws;     // [16384][2048] bf16 (w0^T then w1^T)
  unsigned short* k2T = k1T + 2 * I * H;           // [2048][8192]  bf16
  unsigned short* lnb = k2T + H * I;               // [8192][2048]  bf16
  unsigned short* zb  = lnb + M * H;               // [Mc][8192]    bf16

  const size_t fixedB = (2 * I * H + H * I + M * H) * 2;  // 134.2 MB
  int nc = 1;
  while (nc < 8 && fixedB + (M / nc) * I * 2 > ws_size) nc <<= 1;

  transpose_cast_kernel<<<dim3(H / 32, (2 * I) / 32), 256, 0, stream>>>(
      k1, k1T, (int)H, (int)(2 * I));
  transpose_cast_kernel<<<dim3(I / 32, H / 32), 256, 0, stream>>>(
      k2, k2T, (int)I, (int)H);
  ln_kernel<<<dim3((unsigned)M), 256, 0, stream>>>(x, gamma, beta, lnb);

  const size_t Mc = M / nc;
  for (int c = 0; c < nc; ++c) {
    gemm1_act_kernel<<<dim3((unsigned)(Mc / 128), 64), 256, 0, stream>>>(
        lnb + c * Mc * H, k1T, zb);
    gemm2_kernel<<<dim3((unsigned)(Mc / 128), 16), 256, 0, stream>>>(
        zb, k2T, out + c * Mc * H);
  }
}

// Round 2
// 893.945 us; speedup vs baseline: 1.1429x; 1.1429x over previous
//
#include <hip/hip_runtime.h>
#include <hip/hip_bf16.h>

#define DEVINL __device__ __forceinline__

typedef __attribute__((ext_vector_type(8))) __bf16 bf16x8;
typedef __attribute__((ext_vector_type(4))) float f32x4;
typedef __attribute__((ext_vector_type(4))) unsigned short us4;

DEVINL unsigned short f2bf(float f) {
  union { float f; unsigned int u; } c;
  c.f = f;
  unsigned int u = c.u;
  u += 0x7fffu + ((u >> 16) & 1u);   // RNE
  return (unsigned short)(u >> 16);
}

// jax.nn.gelu(approximate=True) = x * sigmoid(2*sqrt(2/pi)*(x + 0.044715 x^3))
DEVINL float gelu_tanh(float x) {
  float t = 1.5957691216057308f * x * __builtin_fmaf(0.044715f, x * x, 1.0f);
  return x / (1.0f + __expf(-t));
}

DEVINL void ld16(const void* g, void* l) {
  __builtin_amdgcn_global_load_lds(
      (const __attribute__((address_space(1))) void*)g,
      (__attribute__((address_space(3))) void*)l, 16, 0, 0);
}

// ---------------- transpose + fp32->bf16 cast: in[R][C] f32 -> out[C][R] bf16
__global__ __launch_bounds__(256) void transpose_cast_kernel(
    const float* __restrict__ in, unsigned short* __restrict__ out, int R, int C) {
  __shared__ float tile[32][33];
  const int t = threadIdx.x;
  const int r0 = blockIdx.x << 5, c0 = blockIdx.y << 5;
  const int tr = t >> 3, tc = (t & 7) << 2;
  const float4 v = *(const float4*)(in + (size_t)(r0 + tr) * C + c0 + tc);
  tile[tr][tc] = v.x; tile[tr][tc + 1] = v.y;
  tile[tr][tc + 2] = v.z; tile[tr][tc + 3] = v.w;
  __syncthreads();
  us4 o;
  o[0] = f2bf(tile[tc + 0][tr]);
  o[1] = f2bf(tile[tc + 1][tr]);
  o[2] = f2bf(tile[tc + 2][tr]);
  o[3] = f2bf(tile[tc + 3][tr]);
  *(us4*)(out + (size_t)(c0 + tr) * R + r0 + tc) = o;
}

// ---------------- LayerNorm: x[8192][2048] f32 -> ln bf16
__global__ __launch_bounds__(256) void ln_kernel(
    const float* __restrict__ x, const float* __restrict__ gamma,
    const float* __restrict__ beta, unsigned short* __restrict__ out) {
  constexpr int H = 2048;
  const int t = threadIdx.x;
  const size_t row = blockIdx.x;
  const float4* xr = (const float4*)(x + row * H);
  const float4 a = xr[t], b = xr[t + 256];
  float s  = a.x + a.y + a.z + a.w + b.x + b.y + b.z + b.w;
  float s2 = a.x*a.x + a.y*a.y + a.z*a.z + a.w*a.w
           + b.x*b.x + b.y*b.y + b.z*b.z + b.w*b.w;
#pragma unroll
  for (int o = 32; o > 0; o >>= 1) { s += __shfl_xor(s, o); s2 += __shfl_xor(s2, o); }
  __shared__ float red[8];
  const int wid = t >> 6, lane = t & 63;
  if (lane == 0) { red[wid] = s; red[4 + wid] = s2; }
  __syncthreads();
  s  = red[0] + red[1] + red[2] + red[3];
  s2 = red[4] + red[5] + red[6] + red[7];
  const float mean = s * (1.0f / H);
  const float rstd = rsqrtf(s2 * (1.0f / H) - mean * mean + 1e-6f);
  const float4 g0 = ((const float4*)gamma)[t], g1 = ((const float4*)gamma)[t + 256];
  const float4 c0 = ((const float4*)beta)[t],  c1 = ((const float4*)beta)[t + 256];
  us4 o0, o1;
  o0[0] = f2bf((a.x - mean) * rstd * g0.x + c0.x);
  o0[1] = f2bf((a.y - mean) * rstd * g0.y + c0.y);
  o0[2] = f2bf((a.z - mean) * rstd * g0.z + c0.z);
  o0[3] = f2bf((a.w - mean) * rstd * g0.w + c0.w);
  o1[0] = f2bf((b.x - mean) * rstd * g1.x + c1.x);
  o1[1] = f2bf((b.y - mean) * rstd * g1.y + c1.y);
  o1[2] = f2bf((b.z - mean) * rstd * g1.z + c1.z);
  o1[3] = f2bf((b.w - mean) * rstd * g1.w + c1.w);
  *(us4*)(out + row * H + (size_t)t * 4) = o0;
  *(us4*)(out + row * H + 1024 + (size_t)t * 4) = o1;
}

// ---------------- 256-wide 8-phase-style MFMA GEMM (4 phases/K-tile, 2 K-tiles pipelined)
// A [*][KDIM] bf16 K-contig. Bm0/Bm1: B^T row panels (K-contig).
// GATED: block tile = 256 rows x 128 cols, two B mats (gelu(y0)*y1 -> bf16 Z[*,8192])
// else : block tile = 256 x 256, Bm1 = Bm0 + 128 rows (f32 Out[*,2048])
// LDS per buffer: A 32KB | B0 16KB | B1 16KB ; double buffered = 128KB.
// Swizzle (T2, rule 21): linear gload_lds dest; source k-chunk ^= row&7; ds_read chunk ^= row&7.
template<int KDIM, bool GATED>
__global__ __launch_bounds__(512, 2) void gemm8p(
    const unsigned short* __restrict__ Amat,
    const unsigned short* __restrict__ Bm0,
    const unsigned short* __restrict__ Bm1,
    void* __restrict__ outp, int mCount) {
  constexpr int NT = KDIM / 64;
  __shared__ char lds[131072];
  const int t = threadIdx.x, lane = t & 63, wid = t >> 6;
  const int wr = wid >> 2, wc = wid & 3;                // 2 x 4 waves
  // T1: XCD-aware swizzle (grid always % 8 == 0 here)
  const int nwg = (int)gridDim.x, q = nwg >> 3, bid = (int)blockIdx.x;
  const int wg = (bid & 7) * q + (bid >> 3);
  const int mb = wg % mCount, nb = wg / mCount;         // column-major: share B panel
  const size_t m0 = (size_t)mb << 8;
  const size_t nrow = (size_t)nb * (GATED ? 128 : 256);
  const unsigned short* aSrc  = Amat + m0 * KDIM;
  const unsigned short* b0Src = Bm0 + nrow * KDIM;
  const unsigned short* b1Src = Bm1 + nrow * KDIM;

  // staging geometry: unit = 128 rows x 64 k x 2B = 16KB = 2 x ld16/thread
  const int srow = (wid << 3) + (lane >> 3);            // 0..63
  const int sOff = srow * KDIM + (((lane & 7) ^ (srow & 7)) << 3);  // pre-swizzled source

  // fragment read geometry
  const int fr = lane & 15, l16 = lane >> 4;
  const int c0 = (l16 ^ (fr & 7)) << 4;                 // ks=0 chunk byte-off (swizzled)
  const int c1 = ((4 | l16) ^ (fr & 7)) << 4;           // ks=1
  const int aRowOff = ((wr << 6) + fr) << 7;
  const int bRowOff = ((wc << 5) + fr) << 7;

  f32x4 acc[2][2][4][2] = {};                           // [mh][g][m][n]

  auto stageU = [&](const unsigned short* src, int ldsOff, int k0) {
    const unsigned short* s = src + sOff + k0;
    ld16(s, lds + ldsOff + (wid << 10));
    ld16(s + (size_t)64 * KDIM, lds + ldsOff + 8192 + (wid << 10));
  };

#define PHASE(cb_, mh_, g_, STAGE_STMT, VM_STMT)                               \
  {                                                                            \
    const char* ab = lds + (cb_) + (mh_) * 16384;                              \
    const char* bb = lds + (cb_) + 32768 + (g_) * 16384;                       \
    bf16x8 af[2][4], bfr[2][2];                                                \
    _Pragma("unroll") for (int m = 0; m < 4; ++m) {                            \
      af[0][m] = *(const bf16x8*)(ab + aRowOff + m * 2048 + c0);               \
      af[1][m] = *(const bf16x8*)(ab + aRowOff + m * 2048 + c1);               \
    }                                                                          \
    _Pragma("unroll") for (int n = 0; n < 2; ++n) {                            \
      bfr[0][n] = *(const bf16x8*)(bb + bRowOff + n * 2048 + c0);              \
      bfr[1][n] = *(const bf16x8*)(bb + bRowOff + n * 2048 + c1);              \
    }                                                                          \
    STAGE_STMT;                                                                \
    __builtin_amdgcn_s_barrier();                                              \
    asm volatile("s_waitcnt lgkmcnt(0)" ::: "memory");                         \
    __builtin_amdgcn_sched_barrier(0);                                         \
    __builtin_amdgcn_s_setprio(1);                                             \
    _Pragma("unroll") for (int m = 0; m < 4; ++m)                              \
      _Pragma("unroll") for (int n = 0; n < 2; ++n) {                          \
        acc[mh_][g_][m][n] = __builtin_amdgcn_mfma_f32_16x16x32_bf16(          \
            af[0][m], bfr[0][n], acc[mh_][g_][m][n], 0, 0, 0);                 \
        acc[mh_][g_][m][n] = __builtin_amdgcn_mfma_f32_16x16x32_bf16(          \
            af[1][m], bfr[1][n], acc[mh_][g_][m][n], 0, 0, 0);                 \
      }                                                                        \
    __builtin_amdgcn_s_setprio(0);                                             \
    VM_STMT;                                                                   \
    __builtin_amdgcn_s_barrier();                                              \
  }

  // prologue: tile0 (A-lo,B0,A-hi,B1) + tile1 (A-lo,B0); wait all but last 2 units
  stageU(aSrc, 0, 0);
  stageU(b0Src, 32768, 0);
  stageU(aSrc + (size_t)128 * KDIM, 16384, 0);
  stageU(b1Src, 49152, 0);
  stageU(aSrc, 65536, 64);
  stageU(b0Src, 65536 + 32768, 64);
  asm volatile("s_waitcnt vmcnt(4)" ::: "memory");
  __builtin_amdgcn_s_barrier();

  for (int tt = 0; tt < NT; ++tt) {
    const int c = tt & 1, cn = c ^ 1;
    const int t1 = (tt + 1 < NT) ? tt + 1 : NT - 1;
    const int t2 = (tt + 2 < NT) ? tt + 2 : NT - 1;
    const int k1b = t1 << 6, k2b = t2 << 6;
    const int cb = c << 16, cnb = cn << 16;
    // reads: ph1 A-lo,B0 | ph2 A-lo,B1 | ph3 A-hi,B0 | ph4 A-hi,B1
    // stages (slot freed the phase before): A-hi(t+1), B1(t+1), A-lo(t+2), B0(t+2)
    PHASE(cb, 0, 0, stageU(aSrc + (size_t)128 * KDIM, cnb + 16384, k1b), ((void)0));
    PHASE(cb, 0, 1, stageU(b1Src, cnb + 49152, k1b), ((void)0));
    PHASE(cb, 1, 0, stageU(aSrc, cb, k2b), ((void)0));
    PHASE(cb, 1, 1, stageU(b0Src, cb + 32768, k2b),
          asm volatile("s_waitcnt vmcnt(4)" ::: "memory"));
  }
  asm volatile("s_waitcnt vmcnt(0)" ::: "memory");  // drain tail garbage stages
#undef PHASE

  const int fq = (lane >> 4) << 2;
  if constexpr (GATED) {
    unsigned short* Z = (unsigned short*)outp;        // [*, 8192]
#pragma unroll
    for (int mh = 0; mh < 2; ++mh)
#pragma unroll
      for (int m = 0; m < 4; ++m)
#pragma unroll
        for (int n = 0; n < 2; ++n) {
          const size_t row = m0 + (mh << 7) + (wr << 6) + (m << 4) + fq;
          const size_t col = ((size_t)nb << 7) + (wc << 5) + (n << 4) + fr;
#pragma unroll
          for (int rr = 0; rr < 4; ++rr) {
            const float y0 = acc[mh][0][m][n][rr];
            const float y1 = acc[mh][1][m][n][rr];
            Z[(row + rr) * 8192 + col] = f2bf(gelu_tanh(y0) * y1);
          }
        }
  } else {
    float* O = (float*)outp;                          // [*, 2048]
#pragma unroll
    for (int mh = 0; mh < 2; ++mh)
#pragma unroll
      for (int g = 0; g < 2; ++g)
#pragma unroll
        for (int m = 0; m < 4; ++m)
#pragma unroll
          for (int n = 0; n < 2; ++n) {
            const size_t row = m0 + (mh << 7) + (wr << 6) + (m << 4) + fq;
            const size_t col = ((size_t)nb << 8) + (g << 7) + (wc << 5) + (n << 4) + fr;
#pragma unroll
            for (int rr = 0; rr < 4; ++rr)
              O[(row + rr) * 2048 + col] = acc[mh][g][m][n][rr];
          }
  }
}

extern "C" void kernel_launch(void* const* d_in, const int* in_sizes, int n_in,
                              void* d_out, int out_size, void* d_ws, size_t ws_size,
                              hipStream_t stream) {
  const float* x     = (const float*)d_in[0];
  const float* gamma = (const float*)d_in[1];
  const float* beta  = (const float*)d_in[2];
  const float* k1    = (const float*)d_in[3];   // [2048][2][8192] = [2048][16384]
  const float* k2    = (const float*)d_in[4];   // [8192][2048]
  float* out = (float*)d_out;

  const size_t H = 2048, I = 8192, M = 8192;
  unsigned short* k1T = (unsigned short*)d_ws;     // [16384][2048] bf16 (w0^T then w1^T)
  unsigned short* k2T = k1T + 2 * I * H;           // [2048][8192]  bf16
  unsigned short* lnb = k2T + H * I;               // [8192][2048]  bf16
  unsigned short* zb  = lnb + M * H;               // [Mc][8192]    bf16

  const size_t fixedB = (2 * I * H + H * I + M * H) * 2;  // 134.2 MB
  int nc = 1;
  while (nc < 32 && fixedB + (M / nc) * I * 2 > ws_size) nc <<= 1;

  transpose_cast_kernel<<<dim3(H / 32, (2 * I) / 32), 256, 0, stream>>>(
      k1, k1T, (int)H, (int)(2 * I));
  transpose_cast_kernel<<<dim3(I / 32, H / 32), 256, 0, stream>>>(
      k2, k2T, (int)I, (int)H);
  ln_kernel<<<dim3((unsigned)M), 256, 0, stream>>>(x, gamma, beta, lnb);

  const size_t Mc = M / nc;
  const int mC = (int)(Mc / 256);
  for (int c = 0; c < nc; ++c) {
    gemm8p<2048, true><<<dim3((unsigned)(mC * 64)), 512, 0, stream>>>(
        lnb + c * Mc * H, k1T, k1T + (size_t)8192 * 2048, zb, mC);
    gemm8p<8192, false><<<dim3((unsigned)(mC * 8)), 512, 0, stream>>>(
        zb, k2T, k2T + (size_t)128 * 8192, out + c * Mc * H, mC);
  }
}

// Round 3
// 867.876 us; speedup vs baseline: 1.1773x; 1.0300x over previous
//
#include <hip/hip_runtime.h>
#include <hip/hip_bf16.h>

#define DEVINL __device__ __forceinline__

typedef __attribute__((ext_vector_type(8))) __bf16 bf16x8;
typedef __attribute__((ext_vector_type(4))) float f32x4;
typedef __attribute__((ext_vector_type(4))) unsigned short us4;

DEVINL unsigned short f2bf(float f) {
  union { float f; unsigned int u; } c;
  c.f = f;
  unsigned int u = c.u;
  u += 0x7fffu + ((u >> 16) & 1u);   // RNE
  return (unsigned short)(u >> 16);
}

// jax.nn.gelu(approximate=True) = x * sigmoid(2*sqrt(2/pi)*(x + 0.044715 x^3))
DEVINL float gelu_tanh(float x) {
  float t = 1.5957691216057308f * x * __builtin_fmaf(0.044715f, x * x, 1.0f);
  return x / (1.0f + __expf(-t));
}

DEVINL void ld16(const void* g, void* l) {
  __builtin_amdgcn_global_load_lds(
      (const __attribute__((address_space(1))) void*)g,
      (__attribute__((address_space(3))) void*)l, 16, 0, 0);
}

// ---------------- transpose + fp32->bf16 cast: in[R][C] f32 -> out[C][R] bf16
__global__ __launch_bounds__(256) void transpose_cast_kernel(
    const float* __restrict__ in, unsigned short* __restrict__ out, int R, int C) {
  __shared__ float tile[32][33];
  const int t = threadIdx.x;
  const int r0 = blockIdx.x << 5, c0 = blockIdx.y << 5;
  const int tr = t >> 3, tc = (t & 7) << 2;
  const float4 v = *(const float4*)(in + (size_t)(r0 + tr) * C + c0 + tc);
  tile[tr][tc] = v.x; tile[tr][tc + 1] = v.y;
  tile[tr][tc + 2] = v.z; tile[tr][tc + 3] = v.w;
  __syncthreads();
  us4 o;
  o[0] = f2bf(tile[tc + 0][tr]);
  o[1] = f2bf(tile[tc + 1][tr]);
  o[2] = f2bf(tile[tc + 2][tr]);
  o[3] = f2bf(tile[tc + 3][tr]);
  *(us4*)(out + (size_t)(c0 + tr) * R + r0 + tc) = o;
}

// ---------------- LayerNorm: x[8192][2048] f32 -> ln bf16
__global__ __launch_bounds__(256) void ln_kernel(
    const float* __restrict__ x, const float* __restrict__ gamma,
    const float* __restrict__ beta, unsigned short* __restrict__ out) {
  constexpr int H = 2048;
  const int t = threadIdx.x;
  const size_t row = blockIdx.x;
  const float4* xr = (const float4*)(x + row * H);
  const float4 a = xr[t], b = xr[t + 256];
  float s  = a.x + a.y + a.z + a.w + b.x + b.y + b.z + b.w;
  float s2 = a.x*a.x + a.y*a.y + a.z*a.z + a.w*a.w
           + b.x*b.x + b.y*b.y + b.z*b.z + b.w*b.w;
#pragma unroll
  for (int o = 32; o > 0; o >>= 1) { s += __shfl_xor(s, o); s2 += __shfl_xor(s2, o); }
  __shared__ float red[8];
  const int wid = t >> 6, lane = t & 63;
  if (lane == 0) { red[wid] = s; red[4 + wid] = s2; }
  __syncthreads();
  s  = red[0] + red[1] + red[2] + red[3];
  s2 = red[4] + red[5] + red[6] + red[7];
  const float mean = s * (1.0f / H);
  const float rstd = rsqrtf(s2 * (1.0f / H) - mean * mean + 1e-6f);
  const float4 g0 = ((const float4*)gamma)[t], g1 = ((const float4*)gamma)[t + 256];
  const float4 c0 = ((const float4*)beta)[t],  c1 = ((const float4*)beta)[t + 256];
  us4 o0, o1;
  o0[0] = f2bf((a.x - mean) * rstd * g0.x + c0.x);
  o0[1] = f2bf((a.y - mean) * rstd * g0.y + c0.y);
  o0[2] = f2bf((a.z - mean) * rstd * g0.z + c0.z);
  o0[3] = f2bf((a.w - mean) * rstd * g0.w + c0.w);
  o1[0] = f2bf((b.x - mean) * rstd * g1.x + c1.x);
  o1[1] = f2bf((b.y - mean) * rstd * g1.y + c1.y);
  o1[2] = f2bf((b.z - mean) * rstd * g1.z + c1.z);
  o1[3] = f2bf((b.w - mean) * rstd * g1.w + c1.w);
  *(us4*)(out + row * H + (size_t)t * 4) = o0;
  *(us4*)(out + row * H + 1024 + (size_t)t * 4) = o1;
}

// ---------------- 256-wide 8-phase-style MFMA GEMM (4 phases/K-tile, 2 K-tiles pipelined)
// A [*][KDIM] bf16 K-contig. Bm0/Bm1: B^T row panels (K-contig).
// GATED: block tile = 256 rows x 128 cols, two B mats (gelu(y0)*y1 -> bf16 Z[*,8192])
// else : block tile = 256 x 256, Bm1 = Bm0 + 128 rows (f32 Out[*,2048])
// LDS per buffer: A 32KB | B0 16KB | B1 16KB ; double buffered = 128KB.
// Swizzle (T2, rule 21): linear gload_lds dest; source k-chunk ^= row&7; ds_read chunk ^= row&7.
template<int KDIM, bool GATED>
__global__ __launch_bounds__(512, 2) void gemm8p(
    const unsigned short* __restrict__ Amat,
    const unsigned short* __restrict__ Bm0,
    const unsigned short* __restrict__ Bm1,
    void* __restrict__ outp, int mCount) {
  constexpr int NT = KDIM / 64;
  __shared__ char lds[131072];
  const int t = threadIdx.x, lane = t & 63, wid = t >> 6;
  const int wr = wid >> 2, wc = wid & 3;                // 2 x 4 waves
  const int bid = (int)blockIdx.x;
  int mb, nb;
  if (GATED && mCount >= 8) {
    // L2-lockstep 2D chunk map: per XCD, 32 concurrent blocks = 8 mb x 4 nb.
    // B-quad (4MB) + lockstep K-slices stay L2-resident; A K-slice shared by
    // 4 nb-siblings, B K-slice by 8 mb-siblings.
    const int xcd = bid & 7, l = bid >> 3;     // l in [0, mCount*8)
    const int g = l >> 5, l32 = l & 31;        // generations of 32 blocks
    const int mchunks = mCount >> 3;
    const int quad = g / mchunks, mch = g % mchunks;
    mb = (mch << 3) | (l32 & 7);
    nb = (xcd << 3) | (quad << 2) | (l32 >> 3);
  } else {
    // gemm2: q=32 per XCD -> exactly one nb per XCD (B panel 4MB L2-resident)
    const int nwg = (int)gridDim.x, q = nwg >> 3;
    const int wg = (bid & 7) * q + (bid >> 3);
    mb = wg % mCount; nb = wg / mCount;
  }
  const size_t m0 = (size_t)mb << 8;
  const size_t nrow = (size_t)nb * (GATED ? 128 : 256);
  const unsigned short* aSrc  = Amat + m0 * KDIM;
  const unsigned short* b0Src = Bm0 + nrow * KDIM;
  const unsigned short* b1Src = Bm1 + nrow * KDIM;

  // staging geometry: unit = 128 rows x 64 k x 2B = 16KB = 2 x ld16/thread
  const int srow = (wid << 3) + (lane >> 3);            // 0..63
  const int sOff = srow * KDIM + (((lane & 7) ^ (srow & 7)) << 3);  // pre-swizzled source

  // fragment read geometry
  const int fr = lane & 15, l16 = lane >> 4;
  const int c0 = (l16 ^ (fr & 7)) << 4;                 // ks=0 chunk byte-off (swizzled)
  const int c1 = ((4 | l16) ^ (fr & 7)) << 4;           // ks=1
  const int aRowOff = ((wr << 6) + fr) << 7;
  const int bRowOff = ((wc << 5) + fr) << 7;

  f32x4 acc[2][2][4][2] = {};                           // [mh][g][m][n]

  auto stageU = [&](const unsigned short* src, int ldsOff, int k0) {
    const unsigned short* s = src + sOff + k0;
    ld16(s, lds + ldsOff + (wid << 10));
    ld16(s + (size_t)64 * KDIM, lds + ldsOff + 8192 + (wid << 10));
  };

#define PHASE(cb_, mh_, g_, STAGE_STMT, VM_STMT)                               \
  {                                                                            \
    const char* ab = lds + (cb_) + (mh_) * 16384;                              \
    const char* bb = lds + (cb_) + 32768 + (g_) * 16384;                       \
    bf16x8 af[2][4], bfr[2][2];                                                \
    _Pragma("unroll") for (int m = 0; m < 4; ++m) {                            \
      af[0][m] = *(const bf16x8*)(ab + aRowOff + m * 2048 + c0);               \
      af[1][m] = *(const bf16x8*)(ab + aRowOff + m * 2048 + c1);               \
    }                                                                          \
    _Pragma("unroll") for (int n = 0; n < 2; ++n) {                            \
      bfr[0][n] = *(const bf16x8*)(bb + bRowOff + n * 2048 + c0);              \
      bfr[1][n] = *(const bf16x8*)(bb + bRowOff + n * 2048 + c1);              \
    }                                                                          \
    STAGE_STMT;                                                                \
    __builtin_amdgcn_s_barrier();                                              \
    asm volatile("s_waitcnt lgkmcnt(0)" ::: "memory");                         \
    __builtin_amdgcn_sched_barrier(0);                                         \
    __builtin_amdgcn_s_setprio(1);                                             \
    _Pragma("unroll") for (int m = 0; m < 4; ++m)                              \
      _Pragma("unroll") for (int n = 0; n < 2; ++n) {                          \
        acc[mh_][g_][m][n] = __builtin_amdgcn_mfma_f32_16x16x32_bf16(          \
            af[0][m], bfr[0][n], acc[mh_][g_][m][n], 0, 0, 0);                 \
        acc[mh_][g_][m][n] = __builtin_amdgcn_mfma_f32_16x16x32_bf16(          \
            af[1][m], bfr[1][n], acc[mh_][g_][m][n], 0, 0, 0);                 \
      }                                                                        \
    __builtin_amdgcn_s_setprio(0);                                             \
    VM_STMT;                                                                   \
    __builtin_amdgcn_s_barrier();                                              \
  }

  // prologue: tile0 (A-lo,B0,A-hi,B1) + tile1 (A-lo,B0); wait all but last 2 units
  stageU(aSrc, 0, 0);
  stageU(b0Src, 32768, 0);
  stageU(aSrc + (size_t)128 * KDIM, 16384, 0);
  stageU(b1Src, 49152, 0);
  stageU(aSrc, 65536, 64);
  stageU(b0Src, 65536 + 32768, 64);
  asm volatile("s_waitcnt vmcnt(4)" ::: "memory");
  __builtin_amdgcn_s_barrier();

  for (int tt = 0; tt < NT; ++tt) {
    const int c = tt & 1, cn = c ^ 1;
    const int t1 = (tt + 1 < NT) ? tt + 1 : NT - 1;
    const int t2 = (tt + 2 < NT) ? tt + 2 : NT - 1;
    const int k1b = t1 << 6, k2b = t2 << 6;
    const int cb = c << 16, cnb = cn << 16;
    // reads: ph1 A-lo,B0 | ph2 A-lo,B1 | ph3 A-hi,B0 | ph4 A-hi,B1
    // stages (slot freed the phase before): A-hi(t+1), B1(t+1), A-lo(t+2), B0(t+2)
    PHASE(cb, 0, 0, stageU(aSrc + (size_t)128 * KDIM, cnb + 16384, k1b), ((void)0));
    PHASE(cb, 0, 1, stageU(b1Src, cnb + 49152, k1b), ((void)0));
    PHASE(cb, 1, 0, stageU(aSrc, cb, k2b), ((void)0));
    PHASE(cb, 1, 1, stageU(b0Src, cb + 32768, k2b),
          asm volatile("s_waitcnt vmcnt(4)" ::: "memory"));
  }
  asm volatile("s_waitcnt vmcnt(0)" ::: "memory");  // drain tail garbage stages
#undef PHASE

  const int fq = (lane >> 4) << 2;
  if constexpr (GATED) {
    unsigned short* Z = (unsigned short*)outp;        // [*, 8192]
#pragma unroll
    for (int mh = 0; mh < 2; ++mh)
#pragma unroll
      for (int m = 0; m < 4; ++m)
#pragma unroll
        for (int n = 0; n < 2; ++n) {
          const size_t row = m0 + (mh << 7) + (wr << 6) + (m << 4) + fq;
          const size_t col = ((size_t)nb << 7) + (wc << 5) + (n << 4) + fr;
#pragma unroll
          for (int rr = 0; rr < 4; ++rr) {
            const float y0 = acc[mh][0][m][n][rr];
            const float y1 = acc[mh][1][m][n][rr];
            Z[(row + rr) * 8192 + col] = f2bf(gelu_tanh(y0) * y1);
          }
        }
  } else {
    float* O = (float*)outp;                          // [*, 2048]
#pragma unroll
    for (int mh = 0; mh < 2; ++mh)
#pragma unroll
      for (int g = 0; g < 2; ++g)
#pragma unroll
        for (int m = 0; m < 4; ++m)
#pragma unroll
          for (int n = 0; n < 2; ++n) {
            const size_t row = m0 + (mh << 7) + (wr << 6) + (m << 4) + fq;
            const size_t col = ((size_t)nb << 8) + (g << 7) + (wc << 5) + (n << 4) + fr;
#pragma unroll
            for (int rr = 0; rr < 4; ++rr)
              O[(row + rr) * 2048 + col] = acc[mh][g][m][n][rr];
          }
  }
}

extern "C" void kernel_launch(void* const* d_in, const int* in_sizes, int n_in,
                              void* d_out, int out_size, void* d_ws, size_t ws_size,
                              hipStream_t stream) {
  const float* x     = (const float*)d_in[0];
  const float* gamma = (const float*)d_in[1];
  const float* beta  = (const float*)d_in[2];
  const float* k1    = (const float*)d_in[3];   // [2048][2][8192] = [2048][16384]
  const float* k2    = (const float*)d_in[4];   // [8192][2048]
  float* out = (float*)d_out;

  const size_t H = 2048, I = 8192, M = 8192;
  unsigned short* k1T = (unsigned short*)d_ws;     // [16384][2048] bf16 (w0^T then w1^T)
  unsigned short* k2T = k1T + 2 * I * H;           // [2048][8192]  bf16
  unsigned short* lnb = k2T + H * I;               // [8192][2048]  bf16
  unsigned short* zb  = lnb + M * H;               // [Mc][8192]    bf16

  const size_t fixedB = (2 * I * H + H * I + M * H) * 2;  // 134.2 MB
  int nc = 1;
  while (nc < 32 && fixedB + (M / nc) * I * 2 > ws_size) nc <<= 1;

  transpose_cast_kernel<<<dim3(H / 32, (2 * I) / 32), 256, 0, stream>>>(
      k1, k1T, (int)H, (int)(2 * I));
  transpose_cast_kernel<<<dim3(I / 32, H / 32), 256, 0, stream>>>(
      k2, k2T, (int)I, (int)H);
  ln_kernel<<<dim3((unsigned)M), 256, 0, stream>>>(x, gamma, beta, lnb);

  const size_t Mc = M / nc;
  const int mC = (int)(Mc / 256);
  for (int c = 0; c < nc; ++c) {
    gemm8p<2048, true><<<dim3((unsigned)(mC * 64)), 512, 0, stream>>>(
        lnb + c * Mc * H, k1T, k1T + (size_t)8192 * 2048, zb, mC);
    gemm8p<8192, false><<<dim3((unsigned)(mC * 8)), 512, 0, stream>>>(
        zb, k2T, k2T + (size_t)128 * 8192, out + c * Mc * H, mC);
  }
}

// Round 4
// 802.675 us; speedup vs baseline: 1.2729x; 1.0812x over previous
//
#include <hip/hip_runtime.h>
#include <hip/hip_bf16.h>

#define DEVINL __device__ __forceinline__

typedef __attribute__((ext_vector_type(8))) __bf16 bf16x8;
typedef __attribute__((ext_vector_type(4))) float f32x4;
typedef __attribute__((ext_vector_type(4))) unsigned short us4;

DEVINL unsigned short f2bf(float f) {
  union { float f; unsigned int u; } c;
  c.f = f;
  unsigned int u = c.u;
  u += 0x7fffu + ((u >> 16) & 1u);   // RNE
  return (unsigned short)(u >> 16);
}

// jax.nn.gelu(approximate=True) = x * sigmoid(2*sqrt(2/pi)*(x + 0.044715 x^3))
DEVINL float gelu_tanh(float x) {
  float t = 1.5957691216057308f * x * __builtin_fmaf(0.044715f, x * x, 1.0f);
  return x / (1.0f + __expf(-t));
}

DEVINL void ld16(const void* g, void* l) {
  __builtin_amdgcn_global_load_lds(
      (const __attribute__((address_space(1))) void*)g,
      (__attribute__((address_space(3))) void*)l, 16, 0, 0);
}

// ---------------- transpose + fp32->bf16 cast: in[R][C] f32 -> out[C][R] bf16
__global__ __launch_bounds__(256) void transpose_cast_kernel(
    const float* __restrict__ in, unsigned short* __restrict__ out, int R, int C) {
  __shared__ float tile[32][33];
  const int t = threadIdx.x;
  const int r0 = blockIdx.x << 5, c0 = blockIdx.y << 5;
  const int tr = t >> 3, tc = (t & 7) << 2;
  const float4 v = *(const float4*)(in + (size_t)(r0 + tr) * C + c0 + tc);
  tile[tr][tc] = v.x; tile[tr][tc + 1] = v.y;
  tile[tr][tc + 2] = v.z; tile[tr][tc + 3] = v.w;
  __syncthreads();
  us4 o;
  o[0] = f2bf(tile[tc + 0][tr]);
  o[1] = f2bf(tile[tc + 1][tr]);
  o[2] = f2bf(tile[tc + 2][tr]);
  o[3] = f2bf(tile[tc + 3][tr]);
  *(us4*)(out + (size_t)(c0 + tr) * R + r0 + tc) = o;
}

// ---------------- LayerNorm: x[8192][2048] f32 -> ln bf16
__global__ __launch_bounds__(256) void ln_kernel(
    const float* __restrict__ x, const float* __restrict__ gamma,
    const float* __restrict__ beta, unsigned short* __restrict__ out) {
  constexpr int H = 2048;
  const int t = threadIdx.x;
  const size_t row = blockIdx.x;
  const float4* xr = (const float4*)(x + row * H);
  const float4 a = xr[t], b = xr[t + 256];
  float s  = a.x + a.y + a.z + a.w + b.x + b.y + b.z + b.w;
  float s2 = a.x*a.x + a.y*a.y + a.z*a.z + a.w*a.w
           + b.x*b.x + b.y*b.y + b.z*b.z + b.w*b.w;
#pragma unroll
  for (int o = 32; o > 0; o >>= 1) { s += __shfl_xor(s, o); s2 += __shfl_xor(s2, o); }
  __shared__ float red[8];
  const int wid = t >> 6, lane = t & 63;
  if (lane == 0) { red[wid] = s; red[4 + wid] = s2; }
  __syncthreads();
  s  = red[0] + red[1] + red[2] + red[3];
  s2 = red[4] + red[5] + red[6] + red[7];
  const float mean = s * (1.0f / H);
  const float rstd = rsqrtf(s2 * (1.0f / H) - mean * mean + 1e-6f);
  const float4 g0 = ((const float4*)gamma)[t], g1 = ((const float4*)gamma)[t + 256];
  const float4 c0 = ((const float4*)beta)[t],  c1 = ((const float4*)beta)[t + 256];
  us4 o0, o1;
  o0[0] = f2bf((a.x - mean) * rstd * g0.x + c0.x);
  o0[1] = f2bf((a.y - mean) * rstd * g0.y + c0.y);
  o0[2] = f2bf((a.z - mean) * rstd * g0.z + c0.z);
  o0[3] = f2bf((a.w - mean) * rstd * g0.w + c0.w);
  o1[0] = f2bf((b.x - mean) * rstd * g1.x + c1.x);
  o1[1] = f2bf((b.y - mean) * rstd * g1.y + c1.y);
  o1[2] = f2bf((b.z - mean) * rstd * g1.z + c1.z);
  o1[3] = f2bf((b.w - mean) * rstd * g1.w + c1.w);
  *(us4*)(out + row * H + (size_t)t * 4) = o0;
  *(us4*)(out + row * H + 1024 + (size_t)t * 4) = o1;
}

// ---------------- 256-wide 8-phase-style MFMA GEMM (4 phases/K-tile, zig-zag reuse)
// A [*][KDIM] bf16 K-contig. Bm0/Bm1: B^T row panels (K-contig).
// GATED: block tile = 256 rows x 128 cols, two B mats (gelu(y0)*y1 -> bf16 Z[*,8192])
// else : block tile = 256 x 256, Bm1 = Bm0 + 128 rows (f32 Out[*,2048])
// LDS per buffer: A-lo 16K | A-hi 16K | B0 16K | B1 16K ; double buffered = 128KB.
// Phase order (mh,g): (0,0)->(0,1)->(1,1)->(1,0). Each phase changes ONE operand:
// ph1 reads af(A-lo)+bfr(B0)=12, ph2 reads bfr(B1)=4 [af reused], ph3 reads
// af(A-hi)=8 [bfr reused], ph4 reads bfr(B0)=4 [af reused]. 28 ds_read_b128/K-tile
// vs 48 naive -> LDS-pipe cap rises 40% -> ~69%.
// Swizzle (T2, rule 21): linear gload_lds dest; source k-chunk ^= row&7; ds_read chunk ^= row&7.
template<int KDIM, bool GATED>
__global__ __launch_bounds__(512, 2) void gemm8p(
    const unsigned short* __restrict__ Amat,
    const unsigned short* __restrict__ Bm0,
    const unsigned short* __restrict__ Bm1,
    void* __restrict__ outp, int mCount) {
  constexpr int NT = KDIM / 64;
  __shared__ char lds[131072];
  const int t = threadIdx.x, lane = t & 63, wid = t >> 6;
  const int wr = wid >> 2, wc = wid & 3;                // 2 x 4 waves
  const int bid = (int)blockIdx.x;
  int mb, nb;
  if (GATED && mCount >= 8) {
    // L2-lockstep 2D chunk map: per XCD, 32 concurrent blocks = 8 mb x 4 nb.
    const int xcd = bid & 7, l = bid >> 3;
    const int g = l >> 5, l32 = l & 31;
    const int mchunks = mCount >> 3;
    const int quad = g / mchunks, mch = g % mchunks;
    mb = (mch << 3) | (l32 & 7);
    nb = (xcd << 3) | (quad << 2) | (l32 >> 3);
  } else {
    // gemm2: one nb per XCD (B panel 4MB L2-resident)
    const int nwg = (int)gridDim.x, q = nwg >> 3;
    const int wg = (bid & 7) * q + (bid >> 3);
    mb = wg % mCount; nb = wg / mCount;
  }
  const size_t m0 = (size_t)mb << 8;
  const size_t nrow = (size_t)nb * (GATED ? 128 : 256);
  const unsigned short* aSrc  = Amat + m0 * KDIM;
  const unsigned short* b0Src = Bm0 + nrow * KDIM;
  const unsigned short* b1Src = Bm1 + nrow * KDIM;

  // staging geometry: unit = 128 rows x 64 k x 2B = 16KB = 2 x ld16/thread
  const int srow = (wid << 3) + (lane >> 3);            // 0..63
  const int sOff = srow * KDIM + (((lane & 7) ^ (srow & 7)) << 3);  // pre-swizzled source

  // fragment read geometry
  const int fr = lane & 15, l16 = lane >> 4;
  const int c0 = (l16 ^ (fr & 7)) << 4;                 // ks=0 chunk byte-off (swizzled)
  const int c1 = ((4 | l16) ^ (fr & 7)) << 4;           // ks=1
  const int aRowOff = ((wr << 6) + fr) << 7;
  const int bRowOff = ((wc << 5) + fr) << 7;

  f32x4 acc[2][2][4][2] = {};                           // [mh][g][m][n]

  auto stageU = [&](const unsigned short* src, int ldsOff, int k0) {
    const unsigned short* s = src + sOff + k0;
    ld16(s, lds + ldsOff + (wid << 10));
    ld16(s + (size_t)64 * KDIM, lds + ldsOff + 8192 + (wid << 10));
  };

#define READ_A(ab_)                                                           \
  _Pragma("unroll") for (int m = 0; m < 4; ++m) {                             \
    af[0][m] = *(const bf16x8*)((ab_) + aRowOff + m * 2048 + c0);             \
    af[1][m] = *(const bf16x8*)((ab_) + aRowOff + m * 2048 + c1);             \
  }
#define READ_B(bb_)                                                           \
  _Pragma("unroll") for (int n = 0; n < 2; ++n) {                             \
    bfr[0][n] = *(const bf16x8*)((bb_) + bRowOff + n * 2048 + c0);            \
    bfr[1][n] = *(const bf16x8*)((bb_) + bRowOff + n * 2048 + c1);            \
  }
#define MFMA_CLUSTER(mh_, g_)                                                 \
  __builtin_amdgcn_s_barrier();                                               \
  asm volatile("s_waitcnt lgkmcnt(0)" ::: "memory");                          \
  __builtin_amdgcn_sched_barrier(0);                                          \
  __builtin_amdgcn_s_setprio(1);                                              \
  _Pragma("unroll") for (int m = 0; m < 4; ++m)                               \
    _Pragma("unroll") for (int n = 0; n < 2; ++n) {                           \
      acc[mh_][g_][m][n] = __builtin_amdgcn_mfma_f32_16x16x32_bf16(           \
          af[0][m], bfr[0][n], acc[mh_][g_][m][n], 0, 0, 0);                  \
      acc[mh_][g_][m][n] = __builtin_amdgcn_mfma_f32_16x16x32_bf16(           \
          af[1][m], bfr[1][n], acc[mh_][g_][m][n], 0, 0, 0);                  \
    }                                                                         \
  __builtin_amdgcn_s_setprio(0);

  // prologue: tile0 (A-lo,B0,A-hi,B1) + tile1 (A-lo,B0); wait all but last 2 units
  stageU(aSrc, 0, 0);
  stageU(b0Src, 32768, 0);
  stageU(aSrc + (size_t)128 * KDIM, 16384, 0);
  stageU(b1Src, 49152, 0);
  stageU(aSrc, 65536, 64);
  stageU(b0Src, 65536 + 32768, 64);
  asm volatile("s_waitcnt vmcnt(4)" ::: "memory");
  __builtin_amdgcn_s_barrier();

  for (int tt = 0; tt < NT; ++tt) {
    const int c = tt & 1, cn = c ^ 1;
    const int t1 = (tt + 1 < NT) ? tt + 1 : NT - 1;
    const int t2 = (tt + 2 < NT) ? tt + 2 : NT - 1;
    const int k1b = t1 << 6, k2b = t2 << 6;
    const int cb = c << 16, cnb = cn << 16;
    const char* base = lds + cb;
    bf16x8 af[2][4], bfr[2][2];

    // ph1 (mh0,g0): read A-lo + B0; stage A-hi(t+1)
    READ_A(base);
    READ_B(base + 32768);
    stageU(aSrc + (size_t)128 * KDIM, cnb + 16384, k1b);
    MFMA_CLUSTER(0, 0);
    __builtin_amdgcn_s_barrier();

    // ph2 (mh0,g1): af reused; read B1; stage B1(t+1)
    READ_B(base + 49152);
    stageU(b1Src, cnb + 49152, k1b);
    MFMA_CLUSTER(0, 1);
    __builtin_amdgcn_s_barrier();

    // ph3 (mh1,g1): bfr reused; read A-hi; stage A-lo(t+2)
    READ_A(base + 16384);
    stageU(aSrc, cb, k2b);
    MFMA_CLUSTER(1, 1);
    __builtin_amdgcn_s_barrier();

    // ph4 (mh1,g0): af reused; read B0 again; stage B0(t+2); counted vmcnt
    READ_B(base + 32768);
    stageU(b0Src, cb + 32768, k2b);
    MFMA_CLUSTER(1, 0);
    asm volatile("s_waitcnt vmcnt(4)" ::: "memory");
    __builtin_amdgcn_s_barrier();
  }
  asm volatile("s_waitcnt vmcnt(0)" ::: "memory");  // drain tail garbage stages
#undef READ_A
#undef READ_B
#undef MFMA_CLUSTER

  const int fq = (lane >> 4) << 2;
  if constexpr (GATED) {
    unsigned short* Z = (unsigned short*)outp;        // [*, 8192]
#pragma unroll
    for (int mh = 0; mh < 2; ++mh)
#pragma unroll
      for (int m = 0; m < 4; ++m)
#pragma unroll
        for (int n = 0; n < 2; ++n) {
          const size_t row = m0 + (mh << 7) + (wr << 6) + (m << 4) + fq;
          const size_t col = ((size_t)nb << 7) + (wc << 5) + (n << 4) + fr;
#pragma unroll
          for (int rr = 0; rr < 4; ++rr) {
            const float y0 = acc[mh][0][m][n][rr];
            const float y1 = acc[mh][1][m][n][rr];
            Z[(row + rr) * 8192 + col] = f2bf(gelu_tanh(y0) * y1);
          }
        }
  } else {
    float* O = (float*)outp;                          // [*, 2048]
#pragma unroll
    for (int mh = 0; mh < 2; ++mh)
#pragma unroll
      for (int g = 0; g < 2; ++g)
#pragma unroll
        for (int m = 0; m < 4; ++m)
#pragma unroll
          for (int n = 0; n < 2; ++n) {
            const size_t row = m0 + (mh << 7) + (wr << 6) + (m << 4) + fq;
            const size_t col = ((size_t)nb << 8) + (g << 7) + (wc << 5) + (n << 4) + fr;
#pragma unroll
            for (int rr = 0; rr < 4; ++rr)
              O[(row + rr) * 2048 + col] = acc[mh][g][m][n][rr];
          }
  }
}

extern "C" void kernel_launch(void* const* d_in, const int* in_sizes, int n_in,
                              void* d_out, int out_size, void* d_ws, size_t ws_size,
                              hipStream_t stream) {
  const float* x     = (const float*)d_in[0];
  const float* gamma = (const float*)d_in[1];
  const float* beta  = (const float*)d_in[2];
  const float* k1    = (const float*)d_in[3];   // [2048][2][8192] = [2048][16384]
  const float* k2    = (const float*)d_in[4];   // [8192][2048]
  float* out = (float*)d_out;

  const size_t H = 2048, I = 8192, M = 8192;
  unsigned short* k1T = (unsigned short*)d_ws;     // [16384][2048] bf16 (w0^T then w1^T)
  unsigned short* k2T = k1T + 2 * I * H;           // [2048][8192]  bf16
  unsigned short* lnb = k2T + H * I;               // [8192][2048]  bf16
  unsigned short* zb  = lnb + M * H;               // [Mc][8192]    bf16

  const size_t fixedB = (2 * I * H + H * I + M * H) * 2;  // 134.2 MB
  int nc = 1;
  while (nc < 32 && fixedB + (M / nc) * I * 2 > ws_size) nc <<= 1;

  transpose_cast_kernel<<<dim3(H / 32, (2 * I) / 32), 256, 0, stream>>>(
      k1, k1T, (int)H, (int)(2 * I));
  transpose_cast_kernel<<<dim3(I / 32, H / 32), 256, 0, stream>>>(
      k2, k2T, (int)I, (int)H);
  ln_kernel<<<dim3((unsigned)M), 256, 0, stream>>>(x, gamma, beta, lnb);

  const size_t Mc = M / nc;
  const int mC = (int)(Mc / 256);
  for (int c = 0; c < nc; ++c) {
    gemm8p<2048, true><<<dim3((unsigned)(mC * 64)), 512, 0, stream>>>(
        lnb + c * Mc * H, k1T, k1T + (size_t)8192 * 2048, zb, mC);
    gemm8p<8192, false><<<dim3((unsigned)(mC * 8)), 512, 0, stream>>>(
        zb, k2T, k2T + (size_t)128 * 8192, out + c * Mc * H, mC);
  }
}

// Round 5
// 785.350 us; speedup vs baseline: 1.3010x; 1.0221x over previous
//
#include <hip/hip_runtime.h>
#include <hip/hip_bf16.h>

#define DEVINL __device__ __forceinline__

typedef __attribute__((ext_vector_type(8))) __bf16 bf16x8;
typedef __attribute__((ext_vector_type(4))) float f32x4;
typedef __attribute__((ext_vector_type(4))) unsigned short us4;

DEVINL unsigned short f2bf(float f) {
  union { float f; unsigned int u; } c;
  c.f = f;
  unsigned int u = c.u;
  u += 0x7fffu + ((u >> 16) & 1u);   // RNE
  return (unsigned short)(u >> 16);
}

// jax.nn.gelu(approximate=True) = x * sigmoid(2*sqrt(2/pi)*(x + 0.044715 x^3))
DEVINL float gelu_tanh(float x) {
  float t = 1.5957691216057308f * x * __builtin_fmaf(0.044715f, x * x, 1.0f);
  return x / (1.0f + __expf(-t));
}

DEVINL void ld16(const void* g, void* l) {
  __builtin_amdgcn_global_load_lds(
      (const __attribute__((address_space(1))) void*)g,
      (__attribute__((address_space(3))) void*)l, 16, 0, 0);
}

// ---------------- transpose + fp32->bf16 cast: in[R][C] f32 -> out[C][R] bf16
__global__ __launch_bounds__(256) void transpose_cast_kernel(
    const float* __restrict__ in, unsigned short* __restrict__ out, int R, int C) {
  __shared__ float tile[32][33];
  const int t = threadIdx.x;
  const int r0 = blockIdx.x << 5, c0 = blockIdx.y << 5;
  const int tr = t >> 3, tc = (t & 7) << 2;
  const float4 v = *(const float4*)(in + (size_t)(r0 + tr) * C + c0 + tc);
  tile[tr][tc] = v.x; tile[tr][tc + 1] = v.y;
  tile[tr][tc + 2] = v.z; tile[tr][tc + 3] = v.w;
  __syncthreads();
  us4 o;
  o[0] = f2bf(tile[tc + 0][tr]);
  o[1] = f2bf(tile[tc + 1][tr]);
  o[2] = f2bf(tile[tc + 2][tr]);
  o[3] = f2bf(tile[tc + 3][tr]);
  *(us4*)(out + (size_t)(c0 + tr) * R + r0 + tc) = o;
}

// ---------------- LayerNorm: x[8192][2048] f32 -> ln bf16
__global__ __launch_bounds__(256) void ln_kernel(
    const float* __restrict__ x, const float* __restrict__ gamma,
    const float* __restrict__ beta, unsigned short* __restrict__ out) {
  constexpr int H = 2048;
  const int t = threadIdx.x;
  const size_t row = blockIdx.x;
  const float4* xr = (const float4*)(x + row * H);
  const float4 a = xr[t], b = xr[t + 256];
  float s  = a.x + a.y + a.z + a.w + b.x + b.y + b.z + b.w;
  float s2 = a.x*a.x + a.y*a.y + a.z*a.z + a.w*a.w
           + b.x*b.x + b.y*b.y + b.z*b.z + b.w*b.w;
#pragma unroll
  for (int o = 32; o > 0; o >>= 1) { s += __shfl_xor(s, o); s2 += __shfl_xor(s2, o); }
  __shared__ float red[8];
  const int wid = t >> 6, lane = t & 63;
  if (lane == 0) { red[wid] = s; red[4 + wid] = s2; }
  __syncthreads();
  s  = red[0] + red[1] + red[2] + red[3];
  s2 = red[4] + red[5] + red[6] + red[7];
  const float mean = s * (1.0f / H);
  const float rstd = rsqrtf(s2 * (1.0f / H) - mean * mean + 1e-6f);
  const float4 g0 = ((const float4*)gamma)[t], g1 = ((const float4*)gamma)[t + 256];
  const float4 c0 = ((const float4*)beta)[t],  c1 = ((const float4*)beta)[t + 256];
  us4 o0, o1;
  o0[0] = f2bf((a.x - mean) * rstd * g0.x + c0.x);
  o0[1] = f2bf((a.y - mean) * rstd * g0.y + c0.y);
  o0[2] = f2bf((a.z - mean) * rstd * g0.z + c0.z);
  o0[3] = f2bf((a.w - mean) * rstd * g0.w + c0.w);
  o1[0] = f2bf((b.x - mean) * rstd * g1.x + c1.x);
  o1[1] = f2bf((b.y - mean) * rstd * g1.y + c1.y);
  o1[2] = f2bf((b.z - mean) * rstd * g1.z + c1.z);
  o1[3] = f2bf((b.w - mean) * rstd * g1.w + c1.w);
  *(us4*)(out + row * H + (size_t)t * 4) = o0;
  *(us4*)(out + row * H + 1024 + (size_t)t * 4) = o1;
}

// ---------------- 256-wide 4-phase MFMA GEMM, single barrier per phase
// A [*][KDIM] bf16 K-contig. Bm0/Bm1: B^T row panels (K-contig).
// GATED: block tile = 256 rows x 128 cols, two B mats (gelu(y0)*y1 -> bf16 Z[*,8192])
// else : block tile = 256 x 256, Bm1 = Bm0 + 128 rows (f32 Out[*,2048])
// LDS slots per buffer: A-lo | A-hi | B0 | B1 (16K each); double buffered = 128KB.
// Phase order (mh,g): (0,0)->(0,1)->(1,1)->(1,0), af + BOTH bfr sets held in regs:
// reads/K-tile = 12/4/8/0 = 24 ds_read_b128; ph4 is read-free.
// ONE barrier per phase. Safety: each slot's last reader's lgkmcnt(0) precedes
// >=2 barriers before the overwriting stage; vmcnt(4) precedes ph4's barrier so
// tile t+1 data is visible to all waves entering tile t+1.
template<int KDIM, bool GATED>
__global__ __launch_bounds__(512, 2) void gemm8p(
    const unsigned short* __restrict__ Amat,
    const unsigned short* __restrict__ Bm0,
    const unsigned short* __restrict__ Bm1,
    void* __restrict__ outp, int mCount) {
  constexpr int NT = KDIM / 64;
  __shared__ char lds[131072];
  const int t = threadIdx.x, lane = t & 63, wid = t >> 6;
  const int wr = wid >> 2, wc = wid & 3;                // 2 x 4 waves
  const int bid = (int)blockIdx.x;
  int mb, nb;
  if (GATED && mCount >= 8) {
    // L2-lockstep 2D chunk map: per XCD, 32 concurrent blocks = 8 mb x 4 nb.
    const int xcd = bid & 7, l = bid >> 3;
    const int g = l >> 5, l32 = l & 31;
    const int mchunks = mCount >> 3;
    const int quad = g / mchunks, mch = g % mchunks;
    mb = (mch << 3) | (l32 & 7);
    nb = (xcd << 3) | (quad << 2) | (l32 >> 3);
  } else {
    // gemm2: one nb per XCD (B panel 4MB L2-resident)
    const int nwg = (int)gridDim.x, q = nwg >> 3;
    const int wg = (bid & 7) * q + (bid >> 3);
    mb = wg % mCount; nb = wg / mCount;
  }
  const size_t m0 = (size_t)mb << 8;
  const size_t nrow = (size_t)nb * (GATED ? 128 : 256);
  const unsigned short* aSrc  = Amat + m0 * KDIM;
  const unsigned short* b0Src = Bm0 + nrow * KDIM;
  const unsigned short* b1Src = Bm1 + nrow * KDIM;

  // staging geometry: unit = 128 rows x 64 k x 2B = 16KB = 2 x ld16/thread
  const int srow = (wid << 3) + (lane >> 3);            // 0..63
  const int sOff = srow * KDIM + (((lane & 7) ^ (srow & 7)) << 3);  // pre-swizzled source

  // fragment read geometry
  const int fr = lane & 15, l16 = lane >> 4;
  const int c0 = (l16 ^ (fr & 7)) << 4;                 // ks=0 chunk byte-off (swizzled)
  const int c1 = ((4 | l16) ^ (fr & 7)) << 4;           // ks=1
  const int aRowOff = ((wr << 6) + fr) << 7;
  const int bRowOff = ((wc << 5) + fr) << 7;

  f32x4 acc[2][2][4][2] = {};                           // [mh][g][m][n]

  auto stageU = [&](const unsigned short* src, int ldsOff, int k0) {
    const unsigned short* s = src + sOff + k0;
    ld16(s, lds + ldsOff + (wid << 10));
    ld16(s + (size_t)64 * KDIM, lds + ldsOff + 8192 + (wid << 10));
  };

#define READ_A(dst_, ab_)                                                     \
  _Pragma("unroll") for (int m = 0; m < 4; ++m) {                             \
    dst_[0][m] = *(const bf16x8*)((ab_) + aRowOff + m * 2048 + c0);           \
    dst_[1][m] = *(const bf16x8*)((ab_) + aRowOff + m * 2048 + c1);           \
  }
#define READ_B(dst_, bb_)                                                     \
  _Pragma("unroll") for (int n = 0; n < 2; ++n) {                             \
    dst_[0][n] = *(const bf16x8*)((bb_) + bRowOff + n * 2048 + c0);           \
    dst_[1][n] = *(const bf16x8*)((bb_) + bRowOff + n * 2048 + c1);           \
  }
#define MFMA16(mh_, g_, bsrc_)                                                \
  __builtin_amdgcn_s_setprio(1);                                              \
  _Pragma("unroll") for (int m = 0; m < 4; ++m)                               \
    _Pragma("unroll") for (int n = 0; n < 2; ++n) {                           \
      acc[mh_][g_][m][n] = __builtin_amdgcn_mfma_f32_16x16x32_bf16(           \
          af[0][m], bsrc_[0][n], acc[mh_][g_][m][n], 0, 0, 0);                \
      acc[mh_][g_][m][n] = __builtin_amdgcn_mfma_f32_16x16x32_bf16(           \
          af[1][m], bsrc_[1][n], acc[mh_][g_][m][n], 0, 0, 0);                \
    }                                                                         \
  __builtin_amdgcn_s_setprio(0);
#define BAR_LGKM()                                                            \
  __builtin_amdgcn_s_barrier();                                               \
  asm volatile("s_waitcnt lgkmcnt(0)" ::: "memory");                          \
  __builtin_amdgcn_sched_barrier(0);

  // prologue: tile0 (A-lo,B0,A-hi,B1) + tile1 (A-lo,B0); wait all but last 2 units
  stageU(aSrc, 0, 0);
  stageU(b0Src, 32768, 0);
  stageU(aSrc + (size_t)128 * KDIM, 16384, 0);
  stageU(b1Src, 49152, 0);
  stageU(aSrc, 65536, 64);
  stageU(b0Src, 65536 + 32768, 64);
  asm volatile("s_waitcnt vmcnt(4)" ::: "memory");
  __builtin_amdgcn_s_barrier();

  for (int tt = 0; tt < NT; ++tt) {
    const int c = tt & 1, cn = c ^ 1;
    const int t1 = (tt + 1 < NT) ? tt + 1 : NT - 1;
    const int t2 = (tt + 2 < NT) ? tt + 2 : NT - 1;
    const int k1b = t1 << 6, k2b = t2 << 6;
    const int cb = c << 16, cnb = cn << 16;
    const char* base = lds + cb;
    bf16x8 af[2][4], b0r[2][2], b1r[2][2];

    // ph1 (0,0): read A-lo + B0; stage A-hi(t+1)
    READ_A(af, base);
    READ_B(b0r, base + 32768);
    stageU(aSrc + (size_t)128 * KDIM, cnb + 16384, k1b);
    BAR_LGKM();
    MFMA16(0, 0, b0r);

    // ph2 (0,1): af held; read B1; stage B1(t+1)
    READ_B(b1r, base + 49152);
    stageU(b1Src, cnb + 49152, k1b);
    BAR_LGKM();
    MFMA16(0, 1, b1r);

    // ph3 (1,1): b1r held; read A-hi; stage A-lo(t+2)
    READ_A(af, base + 16384);
    stageU(aSrc, cb, k2b);
    BAR_LGKM();
    MFMA16(1, 1, b1r);

    // ph4 (1,0): af + b0r held, NO reads; stage B0(t+2); MFMA overlaps vmcnt
    stageU(b0Src, cb + 32768, k2b);
    MFMA16(1, 0, b0r);
    asm volatile("s_waitcnt vmcnt(4)" ::: "memory");
    __builtin_amdgcn_s_barrier();
  }
  asm volatile("s_waitcnt vmcnt(0)" ::: "memory");  // drain tail garbage stages
#undef READ_A
#undef READ_B
#undef MFMA16
#undef BAR_LGKM

  const int fq = (lane >> 4) << 2;
  if constexpr (GATED) {
    unsigned short* Z = (unsigned short*)outp;        // [*, 8192]
#pragma unroll
    for (int mh = 0; mh < 2; ++mh)
#pragma unroll
      for (int m = 0; m < 4; ++m)
#pragma unroll
        for (int n = 0; n < 2; ++n) {
          const size_t row = m0 + (mh << 7) + (wr << 6) + (m << 4) + fq;
          const size_t col = ((size_t)nb << 7) + (wc << 5) + (n << 4) + fr;
#pragma unroll
          for (int rr = 0; rr < 4; ++rr) {
            const float y0 = acc[mh][0][m][n][rr];
            const float y1 = acc[mh][1][m][n][rr];
            Z[(row + rr) * 8192 + col] = f2bf(gelu_tanh(y0) * y1);
          }
        }
  } else {
    float* O = (float*)outp;                          // [*, 2048]
#pragma unroll
    for (int mh = 0; mh < 2; ++mh)
#pragma unroll
      for (int g = 0; g < 2; ++g)
#pragma unroll
        for (int m = 0; m < 4; ++m)
#pragma unroll
          for (int n = 0; n < 2; ++n) {
            const size_t row = m0 + (mh << 7) + (wr << 6) + (m << 4) + fq;
            const size_t col = ((size_t)nb << 8) + (g << 7) + (wc << 5) + (n << 4) + fr;
#pragma unroll
            for (int rr = 0; rr < 4; ++rr)
              O[(row + rr) * 2048 + col] = acc[mh][g][m][n][rr];
          }
  }
}

extern "C" void kernel_launch(void* const* d_in, const int* in_sizes, int n_in,
                              void* d_out, int out_size, void* d_ws, size_t ws_size,
                              hipStream_t stream) {
  const float* x     = (const float*)d_in[0];
  const float* gamma = (const float*)d_in[1];
  const float* beta  = (const float*)d_in[2];
  const float* k1    = (const float*)d_in[3];   // [2048][2][8192] = [2048][16384]
  const float* k2    = (const float*)d_in[4];   // [8192][2048]
  float* out = (float*)d_out;

  const size_t H = 2048, I = 8192, M = 8192;
  unsigned short* k1T = (unsigned short*)d_ws;     // [16384][2048] bf16 (w0^T then w1^T)
  unsigned short* k2T = k1T + 2 * I * H;           // [2048][8192]  bf16
  unsigned short* lnb = k2T + H * I;               // [8192][2048]  bf16
  unsigned short* zb  = lnb + M * H;               // [Mc][8192]    bf16

  const size_t fixedB = (2 * I * H + H * I + M * H) * 2;  // 134.2 MB
  int nc = 1;
  while (nc < 32 && fixedB + (M / nc) * I * 2 > ws_size) nc <<= 1;

  transpose_cast_kernel<<<dim3(H / 32, (2 * I) / 32), 256, 0, stream>>>(
      k1, k1T, (int)H, (int)(2 * I));
  transpose_cast_kernel<<<dim3(I / 32, H / 32), 256, 0, stream>>>(
      k2, k2T, (int)I, (int)H);
  ln_kernel<<<dim3((unsigned)M), 256, 0, stream>>>(x, gamma, beta, lnb);

  const size_t Mc = M / nc;
  const int mC = (int)(Mc / 256);
  for (int c = 0; c < nc; ++c) {
    gemm8p<2048, true><<<dim3((unsigned)(mC * 64)), 512, 0, stream>>>(
        lnb + c * Mc * H, k1T, k1T + (size_t)8192 * 2048, zb, mC);
    gemm8p<8192, false><<<dim3((unsigned)(mC * 8)), 512, 0, stream>>>(
        zb, k2T, k2T + (size_t)128 * 8192, out + c * Mc * H, mC);
  }
}

// Round 6
// 770.491 us; speedup vs baseline: 1.3261x; 1.0193x over previous
//
#include <hip/hip_runtime.h>
#include <hip/hip_bf16.h>

#define DEVINL __device__ __forceinline__

typedef __attribute__((ext_vector_type(8))) __bf16 bf16x8;
typedef __attribute__((ext_vector_type(4))) float f32x4;
typedef __attribute__((ext_vector_type(4))) unsigned short us4;

DEVINL unsigned short f2bf(float f) {
  union { float f; unsigned int u; } c;
  c.f = f;
  unsigned int u = c.u;
  u += 0x7fffu + ((u >> 16) & 1u);   // RNE
  return (unsigned short)(u >> 16);
}

// jax.nn.gelu(approximate=True) = x * sigmoid(2*sqrt(2/pi)*(x + 0.044715 x^3))
DEVINL float gelu_tanh(float x) {
  float t = 1.5957691216057308f * x * __builtin_fmaf(0.044715f, x * x, 1.0f);
  return x / (1.0f + __expf(-t));
}

DEVINL void ld16(const void* g, void* l) {
  __builtin_amdgcn_global_load_lds(
      (const __attribute__((address_space(1))) void*)g,
      (__attribute__((address_space(3))) void*)l, 16, 0, 0);
}

// ---------------- transpose + fp32->bf16 cast: in[R][C] f32 -> out[C][R] bf16
__global__ __launch_bounds__(256) void transpose_cast_kernel(
    const float* __restrict__ in, unsigned short* __restrict__ out, int R, int C) {
  __shared__ float tile[32][33];
  const int t = threadIdx.x;
  const int r0 = blockIdx.x << 5, c0 = blockIdx.y << 5;
  const int tr = t >> 3, tc = (t & 7) << 2;
  const float4 v = *(const float4*)(in + (size_t)(r0 + tr) * C + c0 + tc);
  tile[tr][tc] = v.x; tile[tr][tc + 1] = v.y;
  tile[tr][tc + 2] = v.z; tile[tr][tc + 3] = v.w;
  __syncthreads();
  us4 o;
  o[0] = f2bf(tile[tc + 0][tr]);
  o[1] = f2bf(tile[tc + 1][tr]);
  o[2] = f2bf(tile[tc + 2][tr]);
  o[3] = f2bf(tile[tc + 3][tr]);
  *(us4*)(out + (size_t)(c0 + tr) * R + r0 + tc) = o;
}

// ---------------- LayerNorm: x[8192][2048] f32 -> ln bf16
__global__ __launch_bounds__(256) void ln_kernel(
    const float* __restrict__ x, const float* __restrict__ gamma,
    const float* __restrict__ beta, unsigned short* __restrict__ out) {
  constexpr int H = 2048;
  const int t = threadIdx.x;
  const size_t row = blockIdx.x;
  const float4* xr = (const float4*)(x + row * H);
  const float4 a = xr[t], b = xr[t + 256];
  float s  = a.x + a.y + a.z + a.w + b.x + b.y + b.z + b.w;
  float s2 = a.x*a.x + a.y*a.y + a.z*a.z + a.w*a.w
           + b.x*b.x + b.y*b.y + b.z*b.z + b.w*b.w;
#pragma unroll
  for (int o = 32; o > 0; o >>= 1) { s += __shfl_xor(s, o); s2 += __shfl_xor(s2, o); }
  __shared__ float red[8];
  const int wid = t >> 6, lane = t & 63;
  if (lane == 0) { red[wid] = s; red[4 + wid] = s2; }
  __syncthreads();
  s  = red[0] + red[1] + red[2] + red[3];
  s2 = red[4] + red[5] + red[6] + red[7];
  const float mean = s * (1.0f / H);
  const float rstd = rsqrtf(s2 * (1.0f / H) - mean * mean + 1e-6f);
  const float4 g0 = ((const float4*)gamma)[t], g1 = ((const float4*)gamma)[t + 256];
  const float4 c0 = ((const float4*)beta)[t],  c1 = ((const float4*)beta)[t + 256];
  us4 o0, o1;
  o0[0] = f2bf((a.x - mean) * rstd * g0.x + c0.x);
  o0[1] = f2bf((a.y - mean) * rstd * g0.y + c0.y);
  o0[2] = f2bf((a.z - mean) * rstd * g0.z + c0.z);
  o0[3] = f2bf((a.w - mean) * rstd * g0.w + c0.w);
  o1[0] = f2bf((b.x - mean) * rstd * g1.x + c1.x);
  o1[1] = f2bf((b.y - mean) * rstd * g1.y + c1.y);
  o1[2] = f2bf((b.z - mean) * rstd * g1.z + c1.z);
  o1[3] = f2bf((b.w - mean) * rstd * g1.w + c1.w);
  *(us4*)(out + row * H + (size_t)t * 4) = o0;
  *(us4*)(out + row * H + 1024 + (size_t)t * 4) = o1;
}

// ---------------- 256-wide tile-pipelined MFMA GEMM, 2 barriers per K-tile
// A [*][KDIM] bf16 K-contig. Bm0/Bm1: B^T row panels (K-contig).
// GATED: block tile = 256 rows x 128 cols, two B mats (gelu(y0)*y1 -> bf16 Z[*,8192])
// else : block tile = 256 x 256, Bm1 = Bm0 + 128 rows (f32 Out[*,2048])
// LDS slots per buffer: A-lo | A-hi | B0 | B1 (16K each); double buffered = 128KB.
// K-tile flow: {16 head reads; stage A-hi(t+1); lgkm(4); MFMA(0,0); lgkm(0);
// MFMA(0,1); re-read af<-A-hi; stage B1(t+1); BAR_B; lgkm(0); MFMA(1,1);
// MFMA(1,0); stage A-lo,B0(t+2); vmcnt(4); BAR_A}. Counted lgkm overlaps
// ds_read bursts with MFMA clusters; reads/K-tile = 24 b128 (minimal).
// Hazard ledger: every slot restage is >=1 barrier after its last reader's
// lgkm-drain; vmcnt(4) before BAR_A guarantees tile t+1 fully staged.
template<int KDIM, bool GATED>
__global__ __launch_bounds__(512, 2) void gemm8p(
    const unsigned short* __restrict__ Amat,
    const unsigned short* __restrict__ Bm0,
    const unsigned short* __restrict__ Bm1,
    void* __restrict__ outp, int mCount) {
  constexpr int NT = KDIM / 64;
  __shared__ char lds[131072];
  const int t = threadIdx.x, lane = t & 63, wid = t >> 6;
  const int wr = wid >> 2, wc = wid & 3;                // 2 x 4 waves
  const int bid = (int)blockIdx.x;
  int mb, nb;
  if (GATED && mCount >= 8) {
    // L2-lockstep 2D chunk map: per XCD, 32 concurrent blocks = 8 mb x 4 nb.
    const int xcd = bid & 7, l = bid >> 3;
    const int g = l >> 5, l32 = l & 31;
    const int mchunks = mCount >> 3;
    const int quad = g / mchunks, mch = g % mchunks;
    mb = (mch << 3) | (l32 & 7);
    nb = (xcd << 3) | (quad << 2) | (l32 >> 3);
  } else {
    // gemm2: one nb per XCD (B panel 4MB L2-resident)
    const int nwg = (int)gridDim.x, q = nwg >> 3;
    const int wg = (bid & 7) * q + (bid >> 3);
    mb = wg % mCount; nb = wg / mCount;
  }
  const size_t m0 = (size_t)mb << 8;
  const size_t nrow = (size_t)nb * (GATED ? 128 : 256);
  const unsigned short* aSrc  = Amat + m0 * KDIM;
  const unsigned short* b0Src = Bm0 + nrow * KDIM;
  const unsigned short* b1Src = Bm1 + nrow * KDIM;

  // staging geometry: unit = 128 rows x 64 k x 2B = 16KB = 2 x ld16/thread
  const int srow = (wid << 3) + (lane >> 3);            // 0..63
  const int sOff = srow * KDIM + (((lane & 7) ^ (srow & 7)) << 3);  // pre-swizzled source

  // fragment read geometry
  const int fr = lane & 15, l16 = lane >> 4;
  const int c0 = (l16 ^ (fr & 7)) << 4;                 // ks=0 chunk byte-off (swizzled)
  const int c1 = ((4 | l16) ^ (fr & 7)) << 4;           // ks=1
  const int aRowOff = ((wr << 6) + fr) << 7;
  const int bRowOff = ((wc << 5) + fr) << 7;

  f32x4 acc[2][2][4][2] = {};                           // [mh][g][m][n]

  auto stageU = [&](const unsigned short* src, int ldsOff, int k0) {
    const unsigned short* s = src + sOff + k0;
    ld16(s, lds + ldsOff + (wid << 10));
    ld16(s + (size_t)64 * KDIM, lds + ldsOff + 8192 + (wid << 10));
  };

#define READ_A(dst_, ab_)                                                     \
  _Pragma("unroll") for (int m = 0; m < 4; ++m) {                             \
    dst_[0][m] = *(const bf16x8*)((ab_) + aRowOff + m * 2048 + c0);           \
    dst_[1][m] = *(const bf16x8*)((ab_) + aRowOff + m * 2048 + c1);           \
  }
#define READ_B(dst_, bb_)                                                     \
  _Pragma("unroll") for (int n = 0; n < 2; ++n) {                             \
    dst_[0][n] = *(const bf16x8*)((bb_) + bRowOff + n * 2048 + c0);           \
    dst_[1][n] = *(const bf16x8*)((bb_) + bRowOff + n * 2048 + c1);           \
  }
#define MFMA16(mh_, g_, bsrc_)                                                \
  __builtin_amdgcn_s_setprio(1);                                              \
  _Pragma("unroll") for (int m = 0; m < 4; ++m)                               \
    _Pragma("unroll") for (int n = 0; n < 2; ++n) {                           \
      acc[mh_][g_][m][n] = __builtin_amdgcn_mfma_f32_16x16x32_bf16(           \
          af[0][m], bsrc_[0][n], acc[mh_][g_][m][n], 0, 0, 0);                \
      acc[mh_][g_][m][n] = __builtin_amdgcn_mfma_f32_16x16x32_bf16(           \
          af[1][m], bsrc_[1][n], acc[mh_][g_][m][n], 0, 0, 0);                \
    }                                                                         \
  __builtin_amdgcn_s_setprio(0);
#define LGKM(n_)                                                              \
  asm volatile("s_waitcnt lgkmcnt(" #n_ ")" ::: "memory");                    \
  __builtin_amdgcn_sched_barrier(0);

  // prologue: tile0 (A-lo,B0,A-hi,B1) + tile1 (A-lo,B0); wait all but last 2 units
  stageU(aSrc, 0, 0);
  stageU(b0Src, 32768, 0);
  stageU(aSrc + (size_t)128 * KDIM, 16384, 0);
  stageU(b1Src, 49152, 0);
  stageU(aSrc, 65536, 64);
  stageU(b0Src, 65536 + 32768, 64);
  asm volatile("s_waitcnt vmcnt(4)" ::: "memory");
  __builtin_amdgcn_s_barrier();

  for (int tt = 0; tt < NT; ++tt) {
    const int c = tt & 1, cn = c ^ 1;
    const int t1 = (tt + 1 < NT) ? tt + 1 : NT - 1;
    const int t2 = (tt + 2 < NT) ? tt + 2 : NT - 1;
    const int k1b = t1 << 6, k2b = t2 << 6;
    const int cb = c << 16, cnb = cn << 16;
    const char* base = lds + cb;
    bf16x8 af[2][4], b0r[2][2], b1r[2][2];

    // head: all 16 fragment reads; stage A-hi(t+1)
    READ_A(af, base);              // A-lo  (8)
    READ_B(b0r, base + 32768);     // B0    (4)
    READ_B(b1r, base + 49152);     // B1    (4)
    stageU(aSrc + (size_t)128 * KDIM, cnb + 16384, k1b);
    LGKM(4);                       // af + b0r done; b1r may fly
    MFMA16(0, 0, b0r);
    LGKM(0);                       // b1r done (landed during MFMA)
    MFMA16(0, 1, b1r);
    READ_A(af, base + 16384);      // A-hi (8), WAR on af — overlaps
    stageU(b1Src, cnb + 49152, k1b);
    __builtin_amdgcn_s_barrier();  // BAR_B
    LGKM(0);                       // af(A-hi) done
    MFMA16(1, 1, b1r);
    MFMA16(1, 0, b0r);
    stageU(aSrc, cb, k2b);         // A-lo(t+2): readers drained pre-BAR_B
    stageU(b0Src, cb + 32768, k2b);// B0(t+2)
    asm volatile("s_waitcnt vmcnt(4)" ::: "memory");  // t+1 fully landed
    __builtin_amdgcn_s_barrier();  // BAR_A
  }
  asm volatile("s_waitcnt vmcnt(0)" ::: "memory");  // drain tail garbage stages
#undef READ_A
#undef READ_B
#undef MFMA16
#undef LGKM

  const int fq = (lane >> 4) << 2;
  if constexpr (GATED) {
    unsigned short* Z = (unsigned short*)outp;        // [*, 8192]
#pragma unroll
    for (int mh = 0; mh < 2; ++mh)
#pragma unroll
      for (int m = 0; m < 4; ++m)
#pragma unroll
        for (int n = 0; n < 2; ++n) {
          const size_t row = m0 + (mh << 7) + (wr << 6) + (m << 4) + fq;
          const size_t col = ((size_t)nb << 7) + (wc << 5) + (n << 4) + fr;
#pragma unroll
          for (int rr = 0; rr < 4; ++rr) {
            const float y0 = acc[mh][0][m][n][rr];
            const float y1 = acc[mh][1][m][n][rr];
            Z[(row + rr) * 8192 + col] = f2bf(gelu_tanh(y0) * y1);
          }
        }
  } else {
    float* O = (float*)outp;                          // [*, 2048]
#pragma unroll
    for (int mh = 0; mh < 2; ++mh)
#pragma unroll
      for (int g = 0; g < 2; ++g)
#pragma unroll
        for (int m = 0; m < 4; ++m)
#pragma unroll
          for (int n = 0; n < 2; ++n) {
            const size_t row = m0 + (mh << 7) + (wr << 6) + (m << 4) + fq;
            const size_t col = ((size_t)nb << 8) + (g << 7) + (wc << 5) + (n << 4) + fr;
#pragma unroll
            for (int rr = 0; rr < 4; ++rr)
              O[(row + rr) * 2048 + col] = acc[mh][g][m][n][rr];
          }
  }
}

extern "C" void kernel_launch(void* const* d_in, const int* in_sizes, int n_in,
                              void* d_out, int out_size, void* d_ws, size_t ws_size,
                              hipStream_t stream) {
  const float* x     = (const float*)d_in[0];
  const float* gamma = (const float*)d_in[1];
  const float* beta  = (const float*)d_in[2];
  const float* k1    = (const float*)d_in[3];   // [2048][2][8192] = [2048][16384]
  const float* k2    = (const float*)d_in[4];   // [8192][2048]
  float* out = (float*)d_out;

  const size_t H = 2048, I = 8192, M = 8192;
  unsigned short* k1T = (unsigned short*)d_ws;     // [16384][2048] bf16 (w0^T then w1^T)
  unsigned short* k2T = k1T + 2 * I * H;           // [2048][8192]  bf16
  unsigned short* lnb = k2T + H * I;               // [8192][2048]  bf16
  unsigned short* zb  = lnb + M * H;               // [Mc][8192]    bf16

  const size_t fixedB = (2 * I * H + H * I + M * H) * 2;  // 134.2 MB
  int nc = 1;
  while (nc < 32 && fixedB + (M / nc) * I * 2 > ws_size) nc <<= 1;

  transpose_cast_kernel<<<dim3(H / 32, (2 * I) / 32), 256, 0, stream>>>(
      k1, k1T, (int)H, (int)(2 * I));
  transpose_cast_kernel<<<dim3(I / 32, H / 32), 256, 0, stream>>>(
      k2, k2T, (int)I, (int)H);
  ln_kernel<<<dim3((unsigned)M), 256, 0, stream>>>(x, gamma, beta, lnb);

  const size_t Mc = M / nc;
  const int mC = (int)(Mc / 256);
  for (int c = 0; c < nc; ++c) {
    gemm8p<2048, true><<<dim3((unsigned)(mC * 64)), 512, 0, stream>>>(
        lnb + c * Mc * H, k1T, k1T + (size_t)8192 * 2048, zb, mC);
    gemm8p<8192, false><<<dim3((unsigned)(mC * 8)), 512, 0, stream>>>(
        zb, k2T, k2T + (size_t)128 * 8192, out + c * Mc * H, mC);
  }
}